// Round 1
// baseline (1223.675 us; speedup 1.0000x reference)
//
#include <hip/hip_runtime.h>
#include <math.h>

#define BB 4
#define TT 2048
#define DD 256
#define FF 1024
#define NL 4

// ---------------- positional encoding add ----------------
__global__ __launch_bounds__(256) void pe_kernel(const float* __restrict__ tokens,
                                                 float* __restrict__ x) {
  int idx = blockIdx.x * 256 + threadIdx.x;      // over B*T*D
  int d = idx & (DD - 1);
  int t = (idx / DD) & (TT - 1);
  int i2 = d & ~1;                               // 2*(d/2)
  float freq = expf((float)i2 * -(9.210340371976184f / 256.f)); // -ln(1e4)/D * 2i
  float ang = (float)t * freq;
  float pe = (d & 1) ? cosf(ang) : sinf(ang);
  x[idx] = tokens[idx] + pe;
}

// ---------------- layernorm (row = 256 floats, 1 wave/row) ----------------
__global__ __launch_bounds__(256) void ln_kernel(const float* __restrict__ x,
                                                 const float* __restrict__ g,
                                                 const float* __restrict__ b,
                                                 float* __restrict__ y) {
  int row = blockIdx.x * 4 + (threadIdx.x >> 6);
  int lane = threadIdx.x & 63;
  const float* xr = x + row * DD;
  float v[4];
  float s = 0.f;
#pragma unroll
  for (int i = 0; i < 4; ++i) { v[i] = xr[lane + 64 * i]; s += v[i]; }
#pragma unroll
  for (int off = 32; off; off >>= 1) s += __shfl_xor(s, off, 64);
  float mu = s * (1.f / DD);
  float vs = 0.f;
#pragma unroll
  for (int i = 0; i < 4; ++i) { float dd = v[i] - mu; vs = fmaf(dd, dd, vs); }
#pragma unroll
  for (int off = 32; off; off >>= 1) vs += __shfl_xor(vs, off, 64);
  float rr = rsqrtf(vs * (1.f / DD) + 1e-5f);
  float* yr = y + row * DD;
#pragma unroll
  for (int i = 0; i < 4; ++i) {
    int d = lane + 64 * i;
    yr[d] = (v[i] - mu) * rr * g[d] + b[d];
  }
}

// ---------------- fp32 GEMM: C[m][n] = act(A[m][k]*B[n][k] + bias[n]) (+res)
// A: M x K row-major, B: N x K row-major (both K-contiguous).
// 64x64 tile per 256-thread block, 4x4 per thread, K-tile 32.
// ACT: 0 none, 1 exact GELU. RES: add res[m][n].
template <int ACT, bool RES>
__global__ __launch_bounds__(256) void gemm_kernel(const float* __restrict__ A,
                                                   const float* __restrict__ B,
                                                   const float* __restrict__ bias,
                                                   const float* res, float* C,
                                                   int M, int N, int K) {
  __shared__ float As[32][68];  // As[k][m], pad 68: float4-aligned, 2-way max
  __shared__ float Bs[32][68];  // Bs[k][n]
  const int tid = threadIdx.x;
  const int tx = tid & 15, ty = tid >> 4;
  const int n0 = blockIdx.x * 64, m0 = blockIdx.y * 64;
  float acc[4][4] = {};
  for (int kt = 0; kt < K; kt += 32) {
    __syncthreads();
#pragma unroll
    for (int it = 0; it < 2; ++it) {
      int f = tid + it * 256;     // float4 index 0..511
      int r = f >> 3;             // row within tile 0..63
      int k4 = f & 7;             // which float4 along k
      float4 a = *(const float4*)&A[(m0 + r) * K + kt + 4 * k4];
      As[4 * k4 + 0][r] = a.x; As[4 * k4 + 1][r] = a.y;
      As[4 * k4 + 2][r] = a.z; As[4 * k4 + 3][r] = a.w;
      float4 bbv = *(const float4*)&B[(n0 + r) * K + kt + 4 * k4];
      Bs[4 * k4 + 0][r] = bbv.x; Bs[4 * k4 + 1][r] = bbv.y;
      Bs[4 * k4 + 2][r] = bbv.z; Bs[4 * k4 + 3][r] = bbv.w;
    }
    __syncthreads();
#pragma unroll
    for (int k = 0; k < 32; ++k) {
      float4 av = *(const float4*)&As[k][4 * ty];
      float4 bv = *(const float4*)&Bs[k][4 * tx];
      float aa[4] = {av.x, av.y, av.z, av.w};
      float bb[4] = {bv.x, bv.y, bv.z, bv.w};
#pragma unroll
      for (int i = 0; i < 4; ++i)
#pragma unroll
        for (int j = 0; j < 4; ++j) acc[i][j] = fmaf(aa[i], bb[j], acc[i][j]);
    }
  }
#pragma unroll
  for (int i = 0; i < 4; ++i) {
    int row = m0 + 4 * ty + i;
    int colb = n0 + 4 * tx;
    float4 rv = make_float4(0.f, 0.f, 0.f, 0.f);
    if (RES) rv = *(const float4*)&res[row * N + colb];
    const float* pr = (const float*)&rv;
    float4 outv;
    float* po = (float*)&outv;
#pragma unroll
    for (int j = 0; j < 4; ++j) {
      float v = acc[i][j] + bias[colb + j];
      if (ACT == 1) v = 0.5f * v * (1.f + erff(v * 0.70710678118654752f));
      if (RES) v += pr[j];
      po[j] = v;
    }
    *(float4*)&C[row * N + colb] = outv;
  }
}

// ---------------- sliding-window attention ----------------
// qkv: (B,T,768) rows [q(256) k(256) v(256)], head h occupies [h*64, h*64+64).
// Block: 256 threads = 4 waves; handles 64 queries for one (b,h).
// Window: key s in [t-63, t] (clamped at 0). Stage 128 key rows in LDS.
__global__ __launch_bounds__(256) void attn_kernel(const float* __restrict__ qkv,
                                                   float* __restrict__ o) {
  __shared__ float KT[64][128];   // KT[d][si]   (si = s - (t0-63))
  __shared__ float Vs[128][64];   // Vs[si][d]
  const int bh = blockIdx.y;
  const int b = bh >> 2, h = bh & 3;
  const int t0 = blockIdx.x * 64;
  const int sbase = t0 - 63;
  const int tid = threadIdx.x;

  const float* kbase = qkv + (b * TT) * 768 + 256 + h * 64;
  const float* vbase = qkv + (b * TT) * 768 + 512 + h * 64;
#pragma unroll
  for (int it = 0; it < 8; ++it) {
    int f = tid + it * 256;       // float4 index 0..2047
    int si = f >> 4;              // 0..127
    int c4 = f & 15;              // float4 within row
    int s = sbase + si;
    float4 kv = make_float4(0.f, 0.f, 0.f, 0.f);
    float4 vv = make_float4(0.f, 0.f, 0.f, 0.f);
    if (s >= 0) {                 // s <= T-1 guaranteed by tiling
      kv = *(const float4*)&kbase[s * 768 + 4 * c4];
      vv = *(const float4*)&vbase[s * 768 + 4 * c4];
    }
    KT[4 * c4 + 0][si] = kv.x; KT[4 * c4 + 1][si] = kv.y;
    KT[4 * c4 + 2][si] = kv.z; KT[4 * c4 + 3][si] = kv.w;
    *(float4*)&Vs[si][4 * c4] = vv;
  }
  __syncthreads();

  const int w = tid >> 6;
  const int lane = tid & 63;
  const float* qbase = qkv + (b * TT) * 768 + h * 64;
  float* obase = o + (b * TT) * DD + h * 64;

  for (int qi = 0; qi < 16; ++qi) {
    int dt = w * 16 + qi;         // t - t0, 0..63
    int tq = t0 + dt;
    float qreg = qbase[tq * 768 + lane];
    // --- scores: lane = key j, key position s = tq - 63 + j ---
    float sc = 0.f;
#pragma unroll
    for (int d = 0; d < 64; ++d) sc = fmaf(__shfl(qreg, d, 64), KT[d][dt + lane], sc);
    sc *= 0.125f;                 // 1/sqrt(64)
    if (tq - 63 + lane < 0) sc = -1e9f;
    // --- softmax over 64 lanes ---
    float m = sc;
#pragma unroll
    for (int off = 32; off; off >>= 1) m = fmaxf(m, __shfl_xor(m, off, 64));
    float p = expf(sc - m);
    float l = p;
#pragma unroll
    for (int off = 32; off; off >>= 1) l += __shfl_xor(l, off, 64);
    p /= l;
    // --- output: lane = dim d ---
    float acc = 0.f;
#pragma unroll
    for (int j = 0; j < 64; ++j) acc = fmaf(__shfl(p, j, 64), Vs[dt + j][lane], acc);
    obase[tq * DD + lane] = acc;
  }
}

extern "C" void kernel_launch(void* const* d_in, const int* in_sizes, int n_in,
                              void* d_out, int out_size, void* d_ws, size_t ws_size,
                              hipStream_t stream) {
  const float* tokens = (const float*)d_in[0];
  const float* Wqkv = (const float*)d_in[1];
  const float* bqkv = (const float*)d_in[2];
  const float* Wo   = (const float*)d_in[3];
  const float* bo   = (const float*)d_in[4];
  const float* W1   = (const float*)d_in[5];
  const float* b1   = (const float*)d_in[6];
  const float* W2   = (const float*)d_in[7];
  const float* b2   = (const float*)d_in[8];
  const float* ln1g = (const float*)d_in[9];
  const float* ln1b = (const float*)d_in[10];
  const float* ln2g = (const float*)d_in[11];
  const float* ln2b = (const float*)d_in[12];
  const float* lnfg = (const float*)d_in[13];
  const float* lnfb = (const float*)d_in[14];
  float* out = (float*)d_out;

  const int ND = BB * TT * DD;          // 2097152
  float* x  = (float*)d_ws;             // residual stream
  float* s1 = x + ND;                   // x2 / attn-out / x3
  float* s2 = s1 + ND;                  // qkv (B*T*768) / ff hidden (B*T*1024)

  const int M = BB * TT;                // 8192

  pe_kernel<<<ND / 256, 256, 0, stream>>>(tokens, x);

  for (int l = 0; l < NL; ++l) {
    ln_kernel<<<M / 4, 256, 0, stream>>>(x, ln1g + l * DD, ln1b + l * DD, s1);
    gemm_kernel<0, false><<<dim3(768 / 64, M / 64), 256, 0, stream>>>(
        s1, Wqkv + l * 768 * DD, bqkv + l * 768, nullptr, s2, M, 768, DD);
    attn_kernel<<<dim3(TT / 64, BB * 4), 256, 0, stream>>>(s2, s1);
    gemm_kernel<0, true><<<dim3(DD / 64, M / 64), 256, 0, stream>>>(
        s1, Wo + l * DD * DD, bo + l * DD, x, x, M, DD, DD);
    ln_kernel<<<M / 4, 256, 0, stream>>>(x, ln2g + l * DD, ln2b + l * DD, s1);
    gemm_kernel<1, false><<<dim3(FF / 64, M / 64), 256, 0, stream>>>(
        s1, W1 + l * FF * DD, b1 + l * FF, nullptr, s2, M, FF, DD);
    gemm_kernel<0, true><<<dim3(DD / 64, M / 64), 256, 0, stream>>>(
        s2, W2 + l * DD * FF, b2 + l * DD, x, x, M, DD, FF);
  }

  ln_kernel<<<M / 4, 256, 0, stream>>>(x, lnfg, lnfb, out);
}

// Round 2
// 658.718 us; speedup vs baseline: 1.8577x; 1.8577x over previous
//
#include <hip/hip_runtime.h>
#include <hip/hip_bf16.h>
#include <math.h>

#define BB 4
#define TT 2048
#define DD 256
#define FF 1024
#define NL 4

typedef __bf16 bf16x8 __attribute__((ext_vector_type(8)));
typedef float f32x4 __attribute__((ext_vector_type(4)));

// ---------------- fp32 -> bf16 convert (weights), 4 elems/thread ----------------
__global__ __launch_bounds__(256) void f2b_kernel(const float4* __restrict__ in,
                                                  ushort4* __restrict__ out) {
  int i = blockIdx.x * 256 + threadIdx.x;
  float4 v = in[i];
  ushort4 o;
  o.x = __hip_bfloat16_raw(__float2bfloat16(v.x)).x;
  o.y = __hip_bfloat16_raw(__float2bfloat16(v.y)).x;
  o.z = __hip_bfloat16_raw(__float2bfloat16(v.z)).x;
  o.w = __hip_bfloat16_raw(__float2bfloat16(v.w)).x;
  out[i] = o;
}

// ---------------- positional encoding add ----------------
__global__ __launch_bounds__(256) void pe_kernel(const float* __restrict__ tokens,
                                                 float* __restrict__ x) {
  int idx = blockIdx.x * 256 + threadIdx.x;      // over B*T*D
  int d = idx & (DD - 1);
  int t = (idx / DD) & (TT - 1);
  int i2 = d & ~1;
  float freq = expf((float)i2 * -(9.210340371976184f / 256.f));
  float ang = (float)t * freq;
  float pe = (d & 1) ? cosf(ang) : sinf(ang);
  x[idx] = tokens[idx] + pe;
}

// ---------------- layernorm (row = 256 floats, 1 wave/row) ----------------
// OBF=1: write bf16, OBF=0: write fp32
template <int OBF>
__global__ __launch_bounds__(256) void ln_kernel(const float* __restrict__ x,
                                                 const float* __restrict__ g,
                                                 const float* __restrict__ b,
                                                 void* __restrict__ yv) {
  int row = blockIdx.x * 4 + (threadIdx.x >> 6);
  int lane = threadIdx.x & 63;
  const float* xr = x + (size_t)row * DD;
  float v[4];
  float s = 0.f;
#pragma unroll
  for (int i = 0; i < 4; ++i) { v[i] = xr[lane + 64 * i]; s += v[i]; }
#pragma unroll
  for (int off = 32; off; off >>= 1) s += __shfl_xor(s, off, 64);
  float mu = s * (1.f / DD);
  float vs = 0.f;
#pragma unroll
  for (int i = 0; i < 4; ++i) { float dd = v[i] - mu; vs = fmaf(dd, dd, vs); }
#pragma unroll
  for (int off = 32; off; off >>= 1) vs += __shfl_xor(vs, off, 64);
  float rr = rsqrtf(vs * (1.f / DD) + 1e-5f);
#pragma unroll
  for (int i = 0; i < 4; ++i) {
    int d = lane + 64 * i;
    float y = (v[i] - mu) * rr * g[d] + b[d];
    if (OBF) ((__hip_bfloat16*)yv)[(size_t)row * DD + d] = __float2bfloat16(y);
    else ((float*)yv)[(size_t)row * DD + d] = y;
  }
}

// ---------------- bf16 MFMA GEMM ----------------
// C[m][n] = act(sum_k A[m][k]*B[n][k] + bias[n]) (+res[m][n])
// A: MxK bf16 row-major, B: NxK bf16 row-major. Block tile (32*MW) x (32*NW),
// 256 threads = 4 waves in 2x2, each wave (16*MW)x(16*NW) via 16x16x32 MFMA.
// Staging via global_load_lds width=16, LDS rows of 32 bf16 (64 B).
template <int MW, int NW, int ACT, int RES, int OBF>
__global__ __launch_bounds__(256) void mgemm_kernel(
    const __hip_bfloat16* __restrict__ A, const __hip_bfloat16* __restrict__ B,
    const float* __restrict__ bias, const float* __restrict__ res,
    void* __restrict__ Cout, int M, int N, int K) {
  constexpr int BM = 32 * MW, BN = 32 * NW;
  constexpr int ROWS = BM + BN;               // multiple of 64
  __shared__ __align__(16) __hip_bfloat16 sm[ROWS * 32];
  const int tid = threadIdx.x;
  const int wave = tid >> 6, lane = tid & 63;
  const int m0 = blockIdx.y * BM, n0 = blockIdx.x * BN;
  const int wm = (wave >> 1) * (16 * MW), wn = (wave & 1) * (16 * NW);
  const int qk = lane >> 4;                   // k-quad 0..3
  const int lr = lane & 15;
  const int srow = lane >> 2;                 // staging row within 16-row group
  const int scol = (lane & 3) * 8;            // staging k offset

  f32x4 acc[MW][NW] = {};

  for (int kt = 0; kt < K; kt += 32) {
    __syncthreads();
#pragma unroll
    for (int i = 0; i < ROWS / 64; ++i) {
      int inst = i * 4 + wave;
      int r = inst * 16 + srow;
      const __hip_bfloat16* g =
          (r < BM) ? (A + (size_t)(m0 + r) * K + kt + scol)
                   : (B + (size_t)(n0 + (r - BM)) * K + kt + scol);
      __builtin_amdgcn_global_load_lds(
          (const __attribute__((address_space(1))) unsigned int*)g,
          (__attribute__((address_space(3))) unsigned int*)(sm + inst * 512),
          16, 0, 0);
    }
    __syncthreads();
    bf16x8 af[MW], bfr[NW];
#pragma unroll
    for (int mi = 0; mi < MW; ++mi)
      af[mi] = *(const bf16x8*)(sm + (wm + mi * 16 + lr) * 32 + qk * 8);
#pragma unroll
    for (int ni = 0; ni < NW; ++ni)
      bfr[ni] = *(const bf16x8*)(sm + (BM + wn + ni * 16 + lr) * 32 + qk * 8);
#pragma unroll
    for (int mi = 0; mi < MW; ++mi)
#pragma unroll
      for (int ni = 0; ni < NW; ++ni)
        acc[mi][ni] = __builtin_amdgcn_mfma_f32_16x16x32_bf16(
            af[mi], bfr[ni], acc[mi][ni], 0, 0, 0);
  }

#pragma unroll
  for (int mi = 0; mi < MW; ++mi) {
#pragma unroll
    for (int ni = 0; ni < NW; ++ni) {
      int col = n0 + wn + ni * 16 + lr;
      float bv = bias[col];
#pragma unroll
      for (int r = 0; r < 4; ++r) {
        int row = m0 + wm + mi * 16 + qk * 4 + r;
        float v = acc[mi][ni][r] + bv;
        if (ACT == 1) v = 0.5f * v * (1.f + erff(v * 0.70710678118654752f));
        if (RES) v += res[(size_t)row * N + col];
        if (OBF) ((__hip_bfloat16*)Cout)[(size_t)row * N + col] = __float2bfloat16(v);
        else ((float*)Cout)[(size_t)row * N + col] = v;
      }
    }
  }
}

// ---------------- sliding-window attention (bf16 I/O, fp32 compute) ----------------
// qkv: (B,T,768) bf16 rows [q k v], head h at [h*64,h*64+64). One block per
// (b,h,64-query tile); stage 128 key/value rows (window span) in LDS fp32.
__global__ __launch_bounds__(256) void attn_kernel(const __hip_bfloat16* __restrict__ qkv,
                                                   __hip_bfloat16* __restrict__ o) {
  __shared__ float KT[64][128];   // KT[d][si], si = s - (t0-63)
  __shared__ float Vs[128][64];   // Vs[si][d]
  const int bh = blockIdx.y;
  const int b = bh >> 2, h = bh & 3;
  const int t0 = blockIdx.x * 64;
  const int sbase = t0 - 63;
  const int tid = threadIdx.x;

  const __hip_bfloat16* kb = qkv + (size_t)(b * TT) * 768 + 256 + h * 64;
  const __hip_bfloat16* vb = kb + 256;
#pragma unroll
  for (int it = 0; it < 4; ++it) {
    int f = tid + it * 256;       // 16B-chunk index 0..1023
    int si = f >> 3;              // 0..127
    int c8 = f & 7;               // chunk within 64-dim row
    int s = sbase + si;
    uint4 kr = make_uint4(0, 0, 0, 0), vr = make_uint4(0, 0, 0, 0);
    if (s >= 0 && s < TT) {
      kr = *(const uint4*)&kb[(size_t)s * 768 + 8 * c8];
      vr = *(const uint4*)&vb[(size_t)s * 768 + 8 * c8];
    }
    unsigned w[4] = {kr.x, kr.y, kr.z, kr.w};
#pragma unroll
    for (int j = 0; j < 4; ++j) {
      KT[8 * c8 + 2 * j][si]     = __uint_as_float(w[j] << 16);
      KT[8 * c8 + 2 * j + 1][si] = __uint_as_float(w[j] & 0xffff0000u);
    }
    unsigned y[4] = {vr.x, vr.y, vr.z, vr.w};
#pragma unroll
    for (int j = 0; j < 4; ++j) {
      Vs[si][8 * c8 + 2 * j]     = __uint_as_float(y[j] << 16);
      Vs[si][8 * c8 + 2 * j + 1] = __uint_as_float(y[j] & 0xffff0000u);
    }
  }
  __syncthreads();

  const int w = tid >> 6;
  const int lane = tid & 63;
  const __hip_bfloat16* qbase = qkv + (size_t)(b * TT) * 768 + h * 64;
  __hip_bfloat16* obase = o + (size_t)(b * TT) * DD + h * 64;

  for (int qi = 0; qi < 16; ++qi) {
    int dt = w * 16 + qi;         // t - t0, 0..63
    int tq = t0 + dt;
    unsigned qu = *(const unsigned short*)&qbase[(size_t)tq * 768 + lane];
    float qreg = __uint_as_float(qu << 16);
    // scores: lane = key j, key pos s = tq - 63 + j
    float sc = 0.f;
#pragma unroll
    for (int d = 0; d < 64; ++d) sc = fmaf(__shfl(qreg, d, 64), KT[d][dt + lane], sc);
    sc *= 0.125f;
    if (tq - 63 + lane < 0) sc = -1e9f;
    float m = sc;
#pragma unroll
    for (int off = 32; off; off >>= 1) m = fmaxf(m, __shfl_xor(m, off, 64));
    float p = expf(sc - m);
    float l = p;
#pragma unroll
    for (int off = 32; off; off >>= 1) l += __shfl_xor(l, off, 64);
    p /= l;
    // output: lane = dim d
    float acc = 0.f;
#pragma unroll
    for (int j = 0; j < 64; ++j) acc = fmaf(__shfl(p, j, 64), Vs[dt + j][lane], acc);
    obase[(size_t)tq * DD + lane] = __float2bfloat16(acc);
  }
}

extern "C" void kernel_launch(void* const* d_in, const int* in_sizes, int n_in,
                              void* d_out, int out_size, void* d_ws, size_t ws_size,
                              hipStream_t stream) {
  const float* tokens = (const float*)d_in[0];
  const float* Wqkv = (const float*)d_in[1];
  const float* bqkv = (const float*)d_in[2];
  const float* Wo   = (const float*)d_in[3];
  const float* bo   = (const float*)d_in[4];
  const float* W1   = (const float*)d_in[5];
  const float* b1   = (const float*)d_in[6];
  const float* W2   = (const float*)d_in[7];
  const float* b2   = (const float*)d_in[8];
  const float* ln1g = (const float*)d_in[9];
  const float* ln1b = (const float*)d_in[10];
  const float* ln2g = (const float*)d_in[11];
  const float* ln2b = (const float*)d_in[12];
  const float* lnfg = (const float*)d_in[13];
  const float* lnfb = (const float*)d_in[14];
  float* out = (float*)d_out;

  const int M = BB * TT;                 // 8192
  const int ND = M * DD;                 // 2097152

  // workspace layout (bytes): x 8MB | sb 4MB | big 16MB | bf16 weights 6.3MB
  float* x = (float*)d_ws;
  __hip_bfloat16* sb  = (__hip_bfloat16*)(x + ND);          // M*256 bf16
  __hip_bfloat16* big = sb + (size_t)M * DD;                // M*1024 bf16 (qkv/h)
  __hip_bfloat16* wqb = big + (size_t)M * FF;
  __hip_bfloat16* wob = wqb + (size_t)NL * 3 * DD * DD;
  __hip_bfloat16* w1b = wob + (size_t)NL * DD * DD;
  __hip_bfloat16* w2b = w1b + (size_t)NL * FF * DD;

  // weight conversion (runs every launch; ~3 us)
  f2b_kernel<<<(NL * 3 * DD * DD) / 1024, 256, 0, stream>>>((const float4*)Wqkv, (ushort4*)wqb);
  f2b_kernel<<<(NL * DD * DD) / 1024, 256, 0, stream>>>((const float4*)Wo, (ushort4*)wob);
  f2b_kernel<<<(NL * FF * DD) / 1024, 256, 0, stream>>>((const float4*)W1, (ushort4*)w1b);
  f2b_kernel<<<(NL * DD * FF) / 1024, 256, 0, stream>>>((const float4*)W2, (ushort4*)w2b);

  pe_kernel<<<ND / 256, 256, 0, stream>>>(tokens, x);

  for (int l = 0; l < NL; ++l) {
    ln_kernel<1><<<M / 4, 256, 0, stream>>>(x, ln1g + l * DD, ln1b + l * DD, sb);
    mgemm_kernel<4, 4, 0, 0, 1><<<dim3(768 / 128, M / 128), 256, 0, stream>>>(
        sb, wqb + (size_t)l * 768 * DD, bqkv + l * 768, nullptr, big, M, 768, DD);
    attn_kernel<<<dim3(TT / 64, BB * 4), 256, 0, stream>>>(big, sb);
    mgemm_kernel<2, 4, 0, 1, 0><<<dim3(DD / 128, M / 64), 256, 0, stream>>>(
        sb, wob + (size_t)l * DD * DD, bo + l * DD, x, x, M, DD, DD);
    ln_kernel<1><<<M / 4, 256, 0, stream>>>(x, ln2g + l * DD, ln2b + l * DD, sb);
    mgemm_kernel<4, 4, 1, 0, 1><<<dim3(FF / 128, M / 128), 256, 0, stream>>>(
        sb, w1b + (size_t)l * FF * DD, b1 + l * FF, nullptr, big, M, FF, DD);
    mgemm_kernel<2, 4, 0, 1, 0><<<dim3(DD / 128, M / 64), 256, 0, stream>>>(
        big, w2b + (size_t)l * DD * FF, b2 + l * DD, x, x, M, DD, FF);
  }

  ln_kernel<0><<<M / 4, 256, 0, stream>>>(x, lnfg, lnfb, out);
}

// Round 3
// 421.131 us; speedup vs baseline: 2.9057x; 1.5642x over previous
//
#include <hip/hip_runtime.h>
#include <hip/hip_bf16.h>
#include <math.h>

#define BB 4
#define TT 2048
#define DD 256
#define FF 1024
#define NL 4

typedef __bf16 bf16x8 __attribute__((ext_vector_type(8)));
typedef float f32x4 __attribute__((ext_vector_type(4)));

// ---------------- fp32 -> bf16 convert (weights), 4 elems/thread ----------------
__global__ __launch_bounds__(256) void f2b_kernel(const float4* __restrict__ in,
                                                  ushort4* __restrict__ out) {
  int i = blockIdx.x * 256 + threadIdx.x;
  float4 v = in[i];
  ushort4 o;
  o.x = __hip_bfloat16_raw(__float2bfloat16(v.x)).x;
  o.y = __hip_bfloat16_raw(__float2bfloat16(v.y)).x;
  o.z = __hip_bfloat16_raw(__float2bfloat16(v.z)).x;
  o.w = __hip_bfloat16_raw(__float2bfloat16(v.w)).x;
  out[i] = o;
}

// ---------------- positional encoding add ----------------
__global__ __launch_bounds__(256) void pe_kernel(const float* __restrict__ tokens,
                                                 float* __restrict__ x) {
  int idx = blockIdx.x * 256 + threadIdx.x;      // over B*T*D
  int d = idx & (DD - 1);
  int t = (idx / DD) & (TT - 1);
  int i2 = d & ~1;
  float freq = expf((float)i2 * -(9.210340371976184f / 256.f));
  float ang = (float)t * freq;
  float pe = (d & 1) ? cosf(ang) : sinf(ang);
  x[idx] = tokens[idx] + pe;
}

// ---------------- layernorm (row = 256 floats, 1 wave/row) ----------------
template <int OBF>
__global__ __launch_bounds__(256) void ln_kernel(const float* __restrict__ x,
                                                 const float* __restrict__ g,
                                                 const float* __restrict__ b,
                                                 void* __restrict__ yv) {
  int row = blockIdx.x * 4 + (threadIdx.x >> 6);
  int lane = threadIdx.x & 63;
  const float* xr = x + (size_t)row * DD;
  float v[4];
  float s = 0.f;
#pragma unroll
  for (int i = 0; i < 4; ++i) { v[i] = xr[lane + 64 * i]; s += v[i]; }
#pragma unroll
  for (int off = 32; off; off >>= 1) s += __shfl_xor(s, off, 64);
  float mu = s * (1.f / DD);
  float vs = 0.f;
#pragma unroll
  for (int i = 0; i < 4; ++i) { float dd = v[i] - mu; vs = fmaf(dd, dd, vs); }
#pragma unroll
  for (int off = 32; off; off >>= 1) vs += __shfl_xor(vs, off, 64);
  float rr = rsqrtf(vs * (1.f / DD) + 1e-5f);
#pragma unroll
  for (int i = 0; i < 4; ++i) {
    int d = lane + 64 * i;
    float y = (v[i] - mu) * rr * g[d] + b[d];
    if (OBF) ((__hip_bfloat16*)yv)[(size_t)row * DD + d] = __float2bfloat16(y);
    else ((float*)yv)[(size_t)row * DD + d] = y;
  }
}

// ---------------- bf16 MFMA GEMM (unchanged from R2) ----------------
template <int MW, int NW, int ACT, int RES, int OBF>
__global__ __launch_bounds__(256) void mgemm_kernel(
    const __hip_bfloat16* __restrict__ A, const __hip_bfloat16* __restrict__ B,
    const float* __restrict__ bias, const float* __restrict__ res,
    void* __restrict__ Cout, int M, int N, int K) {
  constexpr int BM = 32 * MW, BN = 32 * NW;
  constexpr int ROWS = BM + BN;
  __shared__ __align__(16) __hip_bfloat16 sm[ROWS * 32];
  const int tid = threadIdx.x;
  const int wave = tid >> 6, lane = tid & 63;
  const int m0 = blockIdx.y * BM, n0 = blockIdx.x * BN;
  const int wm = (wave >> 1) * (16 * MW), wn = (wave & 1) * (16 * NW);
  const int qk = lane >> 4;
  const int lr = lane & 15;
  const int srow = lane >> 2;
  const int scol = (lane & 3) * 8;

  f32x4 acc[MW][NW] = {};

  for (int kt = 0; kt < K; kt += 32) {
    __syncthreads();
#pragma unroll
    for (int i = 0; i < ROWS / 64; ++i) {
      int inst = i * 4 + wave;
      int r = inst * 16 + srow;
      const __hip_bfloat16* g =
          (r < BM) ? (A + (size_t)(m0 + r) * K + kt + scol)
                   : (B + (size_t)(n0 + (r - BM)) * K + kt + scol);
      __builtin_amdgcn_global_load_lds(
          (const __attribute__((address_space(1))) unsigned int*)g,
          (__attribute__((address_space(3))) unsigned int*)(sm + inst * 512),
          16, 0, 0);
    }
    __syncthreads();
    bf16x8 af[MW], bfr[NW];
#pragma unroll
    for (int mi = 0; mi < MW; ++mi)
      af[mi] = *(const bf16x8*)(sm + (wm + mi * 16 + lr) * 32 + qk * 8);
#pragma unroll
    for (int ni = 0; ni < NW; ++ni)
      bfr[ni] = *(const bf16x8*)(sm + (BM + wn + ni * 16 + lr) * 32 + qk * 8);
#pragma unroll
    for (int mi = 0; mi < MW; ++mi)
#pragma unroll
      for (int ni = 0; ni < NW; ++ni)
        acc[mi][ni] = __builtin_amdgcn_mfma_f32_16x16x32_bf16(
            af[mi], bfr[ni], acc[mi][ni], 0, 0, 0);
  }

#pragma unroll
  for (int mi = 0; mi < MW; ++mi) {
#pragma unroll
    for (int ni = 0; ni < NW; ++ni) {
      int col = n0 + wn + ni * 16 + lr;
      float bv = bias[col];
#pragma unroll
      for (int r = 0; r < 4; ++r) {
        int row = m0 + wm + mi * 16 + qk * 4 + r;
        float v = acc[mi][ni][r] + bv;
        if (ACT == 1) v = 0.5f * v * (1.f + erff(v * 0.70710678118654752f));
        if (RES) v += res[(size_t)row * N + col];
        if (OBF) ((__hip_bfloat16*)Cout)[(size_t)row * N + col] = __float2bfloat16(v);
        else ((float*)Cout)[(size_t)row * N + col] = v;
      }
    }
  }
}

// ---------------- sliding-window attention, MFMA ----------------
// One block per (b, h, 64-query tile). Stage window keys (128 rows) as bf16.
// S(64x128) = Q K^T via mfma 16x16x32; masked fp32 softmax in C-layout regs;
// P -> LDS (A-operand layout, per-wave private); O = P V via mfma with V
// staged transposed. Wave w owns query rows [16w, 16w+16).
__global__ __launch_bounds__(256) void attn_kernel(const __hip_bfloat16* __restrict__ qkv,
                                                   __hip_bfloat16* __restrict__ o) {
  __shared__ __align__(16) __hip_bfloat16 Ks[128][72];    // keys, d-contig (pad 72)
  __shared__ __align__(16) __hip_bfloat16 Vt[64][136];    // V transposed: [d][si]
  __shared__ __align__(16) __hip_bfloat16 Ps[4][16][136]; // P per wave: [row][si]
  const int bh = blockIdx.y;
  const int b = bh >> 2, h = bh & 3;
  const int t0 = blockIdx.x * 64;
  const int sbase = t0 - 63;
  const int tid = threadIdx.x;

  const __hip_bfloat16* kb = qkv + (size_t)(b * TT) * 768 + 256 + h * 64;
  const __hip_bfloat16* vb = kb + 256;
  union U8 { uint4 u; __hip_bfloat16 hx[8]; };
#pragma unroll
  for (int it = 0; it < 4; ++it) {
    int f = tid + it * 256;       // 16B-chunk index 0..1023
    int si = f >> 3;              // 0..127
    int c8 = f & 7;               // chunk within 64-d row
    int s = sbase + si;
    U8 kr, vr;
    kr.u = make_uint4(0, 0, 0, 0); vr.u = make_uint4(0, 0, 0, 0);
    if (s >= 0 && s < TT) {
      kr.u = *(const uint4*)&kb[(size_t)s * 768 + 8 * c8];
      vr.u = *(const uint4*)&vb[(size_t)s * 768 + 8 * c8];
    }
    *(uint4*)&Ks[si][c8 * 8] = kr.u;
#pragma unroll
    for (int j = 0; j < 8; ++j) Vt[c8 * 8 + j][si] = vr.hx[j];
  }
  __syncthreads();

  const int wave = tid >> 6, lane = tid & 63;
  const int quad = lane >> 4, lr = lane & 15;

  // --- QK^T: wave computes S[16][128] for rows t0+16w+0..15 ---
  const __hip_bfloat16* qrow = qkv + (size_t)(b * TT + t0 + wave * 16 + lr) * 768 + h * 64;
  bf16x8 qa0 = *(const bf16x8*)(qrow + quad * 8);
  bf16x8 qa1 = *(const bf16x8*)(qrow + 32 + quad * 8);
  f32x4 sc[8];
#pragma unroll
  for (int c = 0; c < 8; ++c) {
    f32x4 a = {};
    bf16x8 kf0 = *(const bf16x8*)&Ks[c * 16 + lr][quad * 8];
    a = __builtin_amdgcn_mfma_f32_16x16x32_bf16(qa0, kf0, a, 0, 0, 0);
    bf16x8 kf1 = *(const bf16x8*)&Ks[c * 16 + lr][32 + quad * 8];
    a = __builtin_amdgcn_mfma_f32_16x16x32_bf16(qa1, kf1, a, 0, 0, 0);
    sc[c] = a;
  }

  // --- masked softmax per row (reg picks row; reduce across 16 lr lanes) ---
#pragma unroll
  for (int reg = 0; reg < 4; ++reg) {
    int dt = wave * 16 + quad * 4 + reg;     // local query row
    float pv[8];
    float mx = -1e30f;
#pragma unroll
    for (int c = 0; c < 8; ++c) {
      int si = c * 16 + lr;
      float v = sc[c][reg] * 0.125f;
      bool ok = (si >= dt) && (si <= dt + 63) && (sbase + si >= 0);
      v = ok ? v : -1e30f;
      pv[c] = v;
      mx = fmaxf(mx, v);
    }
#pragma unroll
    for (int off = 8; off; off >>= 1) mx = fmaxf(mx, __shfl_xor(mx, off, 64));
    float l = 0.f;
#pragma unroll
    for (int c = 0; c < 8; ++c) { float e = __expf(pv[c] - mx); pv[c] = e; l += e; }
#pragma unroll
    for (int off = 8; off; off >>= 1) l += __shfl_xor(l, off, 64);
    float rinv = 1.f / l;
#pragma unroll
    for (int c = 0; c < 8; ++c)
      Ps[wave][quad * 4 + reg][c * 16 + lr] = __float2bfloat16(pv[c] * rinv);
  }
  // Ps region is per-wave private: no barrier needed.

  // --- O = P V ---
  __hip_bfloat16* obase = o + (size_t)(b * TT) * DD + h * 64;
#pragma unroll
  for (int ct = 0; ct < 4; ++ct) {
    f32x4 acc = {};
#pragma unroll
    for (int kk = 0; kk < 4; ++kk) {
      bf16x8 pa = *(const bf16x8*)&Ps[wave][lr][kk * 32 + quad * 8];
      bf16x8 vf = *(const bf16x8*)&Vt[ct * 16 + lr][kk * 32 + quad * 8];
      acc = __builtin_amdgcn_mfma_f32_16x16x32_bf16(pa, vf, acc, 0, 0, 0);
    }
#pragma unroll
    for (int reg = 0; reg < 4; ++reg) {
      int t = t0 + wave * 16 + quad * 4 + reg;
      obase[(size_t)t * DD + ct * 16 + lr] = __float2bfloat16(acc[reg]);
    }
  }
}

extern "C" void kernel_launch(void* const* d_in, const int* in_sizes, int n_in,
                              void* d_out, int out_size, void* d_ws, size_t ws_size,
                              hipStream_t stream) {
  const float* tokens = (const float*)d_in[0];
  const float* Wqkv = (const float*)d_in[1];
  const float* bqkv = (const float*)d_in[2];
  const float* Wo   = (const float*)d_in[3];
  const float* bo   = (const float*)d_in[4];
  const float* W1   = (const float*)d_in[5];
  const float* b1   = (const float*)d_in[6];
  const float* W2   = (const float*)d_in[7];
  const float* b2   = (const float*)d_in[8];
  const float* ln1g = (const float*)d_in[9];
  const float* ln1b = (const float*)d_in[10];
  const float* ln2g = (const float*)d_in[11];
  const float* ln2b = (const float*)d_in[12];
  const float* lnfg = (const float*)d_in[13];
  const float* lnfb = (const float*)d_in[14];
  float* out = (float*)d_out;

  const int M = BB * TT;                 // 8192
  const int ND = M * DD;                 // 2097152

  float* x = (float*)d_ws;
  __hip_bfloat16* sb  = (__hip_bfloat16*)(x + ND);          // M*256 bf16
  __hip_bfloat16* big = sb + (size_t)M * DD;                // M*1024 bf16
  __hip_bfloat16* wqb = big + (size_t)M * FF;
  __hip_bfloat16* wob = wqb + (size_t)NL * 3 * DD * DD;
  __hip_bfloat16* w1b = wob + (size_t)NL * DD * DD;
  __hip_bfloat16* w2b = w1b + (size_t)NL * FF * DD;

  f2b_kernel<<<(NL * 3 * DD * DD) / 1024, 256, 0, stream>>>((const float4*)Wqkv, (ushort4*)wqb);
  f2b_kernel<<<(NL * DD * DD) / 1024, 256, 0, stream>>>((const float4*)Wo, (ushort4*)wob);
  f2b_kernel<<<(NL * FF * DD) / 1024, 256, 0, stream>>>((const float4*)W1, (ushort4*)w1b);
  f2b_kernel<<<(NL * DD * FF) / 1024, 256, 0, stream>>>((const float4*)W2, (ushort4*)w2b);

  pe_kernel<<<ND / 256, 256, 0, stream>>>(tokens, x);

  for (int l = 0; l < NL; ++l) {
    ln_kernel<1><<<M / 4, 256, 0, stream>>>(x, ln1g + l * DD, ln1b + l * DD, sb);
    mgemm_kernel<4, 4, 0, 0, 1><<<dim3(768 / 128, M / 128), 256, 0, stream>>>(
        sb, wqb + (size_t)l * 768 * DD, bqkv + l * 768, nullptr, big, M, 768, DD);
    attn_kernel<<<dim3(TT / 64, BB * 4), 256, 0, stream>>>(big, sb);
    mgemm_kernel<2, 4, 0, 1, 0><<<dim3(DD / 128, M / 64), 256, 0, stream>>>(
        sb, wob + (size_t)l * DD * DD, bo + l * DD, x, x, M, DD, DD);
    ln_kernel<1><<<M / 4, 256, 0, stream>>>(x, ln2g + l * DD, ln2b + l * DD, sb);
    mgemm_kernel<4, 4, 1, 0, 1><<<dim3(FF / 128, M / 128), 256, 0, stream>>>(
        sb, w1b + (size_t)l * FF * DD, b1 + l * FF, nullptr, big, M, FF, DD);
    mgemm_kernel<2, 4, 0, 1, 0><<<dim3(DD / 128, M / 64), 256, 0, stream>>>(
        big, w2b + (size_t)l * DD * FF, b2 + l * DD, x, x, M, DD, FF);
  }

  ln_kernel<0><<<M / 4, 256, 0, stream>>>(x, lnfg, lnfb, out);
}

// Round 5
// 388.881 us; speedup vs baseline: 3.1467x; 1.0829x over previous
//
#include <hip/hip_runtime.h>
#include <hip/hip_bf16.h>
#include <math.h>

#define BB 4
#define TT 2048
#define DD 256
#define FF 1024
#define NL 4

typedef __bf16 bf16x8 __attribute__((ext_vector_type(8)));
typedef float f32x4 __attribute__((ext_vector_type(4)));

// ---------------- fp32 -> bf16 convert, ALL weights in one kernel ----------------
// dst regions contiguous: wqb | wob | w1b | w2b. Sizes in float4 units:
// 196608 | 65536 | 262144 | 262144 (cum: 196608, 262144, 524288, 786432)
__global__ __launch_bounds__(256) void f2b_all_kernel(const float4* __restrict__ wq,
                                                      const float4* __restrict__ wo,
                                                      const float4* __restrict__ w1,
                                                      const float4* __restrict__ w2,
                                                      ushort4* __restrict__ dst) {
  int gi = blockIdx.x * 256 + threadIdx.x;
  const float4* src;
  int off;
  if (gi < 196608)      { src = wq; off = gi; }
  else if (gi < 262144) { src = wo; off = gi - 196608; }
  else if (gi < 524288) { src = w1; off = gi - 262144; }
  else                  { src = w2; off = gi - 524288; }
  float4 v = src[off];
  ushort4 o;
  o.x = __hip_bfloat16_raw(__float2bfloat16(v.x)).x;
  o.y = __hip_bfloat16_raw(__float2bfloat16(v.y)).x;
  o.z = __hip_bfloat16_raw(__float2bfloat16(v.z)).x;
  o.w = __hip_bfloat16_raw(__float2bfloat16(v.w)).x;
  dst[gi] = o;
}

// ---------------- PE add + LN (layer-0 ln1), 1 wave/row ----------------
__global__ __launch_bounds__(256) void pe_ln_kernel(const float* __restrict__ tokens,
                                                    const float* __restrict__ g,
                                                    const float* __restrict__ b,
                                                    float* __restrict__ x,
                                                    __hip_bfloat16* __restrict__ sb) {
  int row = blockIdx.x * 4 + (threadIdx.x >> 6);
  int lane = threadIdx.x & 63;
  int t = row & (TT - 1);
  const float* xr = tokens + (size_t)row * DD;
  float v[4];
  float s = 0.f;
#pragma unroll
  for (int i = 0; i < 4; ++i) {
    int d = lane + 64 * i;
    int i2 = d & ~1;
    float freq = expf((float)i2 * -(9.210340371976184f / 256.f));
    float ang = (float)t * freq;
    float pe = (d & 1) ? cosf(ang) : sinf(ang);
    v[i] = xr[d] + pe;
    s += v[i];
  }
#pragma unroll
  for (int off = 32; off; off >>= 1) s += __shfl_xor(s, off, 64);
  float mu = s * (1.f / DD);
  float vs = 0.f;
#pragma unroll
  for (int i = 0; i < 4; ++i) { float dd = v[i] - mu; vs = fmaf(dd, dd, vs); }
#pragma unroll
  for (int off = 32; off; off >>= 1) vs += __shfl_xor(vs, off, 64);
  float rr = rsqrtf(vs * (1.f / DD) + 1e-5f);
#pragma unroll
  for (int i = 0; i < 4; ++i) {
    int d = lane + 64 * i;
    x[(size_t)row * DD + d] = v[i];
    sb[(size_t)row * DD + d] = __float2bfloat16((v[i] - mu) * rr * g[d] + b[d]);
  }
}

// ---------------- bf16 MFMA GEMM (general; qkv and W1) ----------------
// C[m][n] = act(sum_k A[m][k]*B[n][k] + bias[n]); A,B row-major K-contig.
template <int MW, int NW, int ACT>
__global__ __launch_bounds__(256) void mgemm_kernel(
    const __hip_bfloat16* __restrict__ A, const __hip_bfloat16* __restrict__ B,
    const float* __restrict__ bias, __hip_bfloat16* __restrict__ Cout,
    int M, int N, int K) {
  constexpr int BM = 32 * MW, BN = 32 * NW;
  constexpr int ROWS = BM + BN;
  constexpr int NINST = ROWS / 16;            // 16 rows staged per instr
  __shared__ __align__(16) __hip_bfloat16 sm[ROWS * 32];
  const int tid = threadIdx.x;
  const int wave = tid >> 6, lane = tid & 63;
  const int m0 = blockIdx.y * BM, n0 = blockIdx.x * BN;
  const int wm = (wave >> 1) * (16 * MW), wn = (wave & 1) * (16 * NW);
  const int qk = lane >> 4;
  const int lr = lane & 15;
  const int srow = lane >> 2;
  const int scol = (lane & 3) * 8;

  f32x4 acc[MW][NW] = {};

  for (int kt = 0; kt < K; kt += 32) {
    __syncthreads();
#pragma unroll
    for (int i = 0; i < (NINST + 3) / 4; ++i) {
      int inst = i * 4 + wave;
      if (inst < NINST) {
        int r = inst * 16 + srow;
        const __hip_bfloat16* g =
            (r < BM) ? (A + (size_t)(m0 + r) * K + kt + scol)
                     : (B + (size_t)(n0 + (r - BM)) * K + kt + scol);
        __builtin_amdgcn_global_load_lds(
            (const __attribute__((address_space(1))) unsigned int*)g,
            (__attribute__((address_space(3))) unsigned int*)(sm + inst * 512),
            16, 0, 0);
      }
    }
    __syncthreads();
    bf16x8 af[MW], bfr[NW];
#pragma unroll
    for (int mi = 0; mi < MW; ++mi)
      af[mi] = *(const bf16x8*)(sm + (wm + mi * 16 + lr) * 32 + qk * 8);
#pragma unroll
    for (int ni = 0; ni < NW; ++ni)
      bfr[ni] = *(const bf16x8*)(sm + (BM + wn + ni * 16 + lr) * 32 + qk * 8);
#pragma unroll
    for (int mi = 0; mi < MW; ++mi)
#pragma unroll
      for (int ni = 0; ni < NW; ++ni)
        acc[mi][ni] = __builtin_amdgcn_mfma_f32_16x16x32_bf16(
            af[mi], bfr[ni], acc[mi][ni], 0, 0, 0);
  }

#pragma unroll
  for (int mi = 0; mi < MW; ++mi) {
#pragma unroll
    for (int ni = 0; ni < NW; ++ni) {
      int col = n0 + wn + ni * 16 + lr;
      float bv = bias[col];
#pragma unroll
      for (int r = 0; r < 4; ++r) {
        int row = m0 + wm + mi * 16 + qk * 4 + r;
        float v = acc[mi][ni][r] + bv;
        if (ACT == 1) v = 0.5f * v * (1.f + erff(v * 0.70710678118654752f));
        Cout[(size_t)row * N + col] = __float2bfloat16(v);
      }
    }
  }
}

// ---------------- bf16 MFMA GEMM, N=256 full-row, fused residual + LayerNorm ----
// BM=16, BN=256, BK=32; grid = M/16. Wave w owns cols [64w, 64w+64) = 4 tiles.
// v = acc + bias + res; x = v (residual); y = LN(v)*g + b -> bf16 (FIN=0) or
// fp32 d_out (FIN=1, no x write).
template <int FIN>
__global__ __launch_bounds__(256) void mgemm_ln_kernel(
    const __hip_bfloat16* __restrict__ A, const __hip_bfloat16* __restrict__ B,
    const float* __restrict__ bias, const float* __restrict__ res,
    const float* __restrict__ g, const float* __restrict__ bb,
    float* __restrict__ xout, void* __restrict__ yout, int K) {
  constexpr int NINST = 17;                    // (16+256)/16
  __shared__ __align__(16) __hip_bfloat16 sm[(16 + 256) * 32];
  __shared__ float red1[4][16], red2[4][16];
  const int tid = threadIdx.x;
  const int wave = tid >> 6, lane = tid & 63;
  const int quad = lane >> 4, lr = lane & 15;
  const int m0 = blockIdx.x * 16;
  const int srow = lane >> 2, scol = (lane & 3) * 8;

  f32x4 acc[4] = {};

  for (int kt = 0; kt < K; kt += 32) {
    __syncthreads();
#pragma unroll
    for (int i = 0; i < 5; ++i) {
      int inst = i * 4 + wave;
      if (inst < NINST) {
        int r = inst * 16 + srow;
        const __hip_bfloat16* gp =
            (r < 16) ? (A + (size_t)(m0 + r) * K + kt + scol)
                     : (B + (size_t)(r - 16) * K + kt + scol);
        __builtin_amdgcn_global_load_lds(
            (const __attribute__((address_space(1))) unsigned int*)gp,
            (__attribute__((address_space(3))) unsigned int*)(sm + inst * 512),
            16, 0, 0);
      }
    }
    __syncthreads();
    bf16x8 af = *(const bf16x8*)(sm + lr * 32 + quad * 8);
    bf16x8 bfr[4];
#pragma unroll
    for (int ni = 0; ni < 4; ++ni)
      bfr[ni] = *(const bf16x8*)(sm + (16 + wave * 64 + ni * 16 + lr) * 32 + quad * 8);
#pragma unroll
    for (int ni = 0; ni < 4; ++ni)
      acc[ni] = __builtin_amdgcn_mfma_f32_16x16x32_bf16(af, bfr[ni], acc[ni], 0, 0, 0);
  }

  // epilogue: v = acc + bias + res; LN over full 256-col rows
  float v[4][4];
  float s1[4] = {}, s2[4] = {};
#pragma unroll
  for (int ni = 0; ni < 4; ++ni) {
    int col = wave * 64 + ni * 16 + lr;
    float bv = bias[col];
#pragma unroll
    for (int r = 0; r < 4; ++r) {
      int row = m0 + quad * 4 + r;
      float val = acc[ni][r] + bv + res[(size_t)row * DD + col];
      v[ni][r] = val;
      s1[r] += val;
      s2[r] = fmaf(val, val, s2[r]);
    }
  }
#pragma unroll
  for (int r = 0; r < 4; ++r) {
#pragma unroll
    for (int off = 8; off; off >>= 1) {
      s1[r] += __shfl_xor(s1[r], off, 64);
      s2[r] += __shfl_xor(s2[r], off, 64);
    }
  }
  if (lr == 0) {
#pragma unroll
    for (int r = 0; r < 4; ++r) {
      red1[wave][quad * 4 + r] = s1[r];
      red2[wave][quad * 4 + r] = s2[r];
    }
  }
  __syncthreads();
#pragma unroll
  for (int r = 0; r < 4; ++r) {
    int rl = quad * 4 + r;
    float ssum = red1[0][rl] + red1[1][rl] + red1[2][rl] + red1[3][rl];
    float qsum = red2[0][rl] + red2[1][rl] + red2[2][rl] + red2[3][rl];
    float mu = ssum * (1.f / DD);
    float var = qsum * (1.f / DD) - mu * mu;
    float rr = rsqrtf(var + 1e-5f);
    int row = m0 + rl;
#pragma unroll
    for (int ni = 0; ni < 4; ++ni) {
      int col = wave * 64 + ni * 16 + lr;
      float y = (v[ni][r] - mu) * rr * g[col] + bb[col];
      if (FIN) {
        ((float*)yout)[(size_t)row * DD + col] = y;
      } else {
        ((__hip_bfloat16*)yout)[(size_t)row * DD + col] = __float2bfloat16(y);
        xout[(size_t)row * DD + col] = v[ni][r];
      }
    }
  }
}

// ---------------- sliding-window attention, MFMA (Vt XOR-swizzled) ----------------
__global__ __launch_bounds__(256) void attn_kernel(const __hip_bfloat16* __restrict__ qkv,
                                                   __hip_bfloat16* __restrict__ o) {
  __shared__ __align__(16) __hip_bfloat16 Ks[128][72];    // keys, d-contig
  __shared__ __align__(16) __hip_bfloat16 Vt[64 * 136];   // V^T, si-chunk XOR d>>3
  __shared__ __align__(16) __hip_bfloat16 Ps[4][16][136]; // P per wave
  const int bh = blockIdx.y;
  const int b = bh >> 2, h = bh & 3;
  const int t0 = blockIdx.x * 64;
  const int sbase = t0 - 63;
  const int tid = threadIdx.x;

  const __hip_bfloat16* kb = qkv + (size_t)(b * TT) * 768 + 256 + h * 64;
  const __hip_bfloat16* vb = kb + 256;
  union U8 { uint4 u; __hip_bfloat16 hx[8]; };
#pragma unroll
  for (int it = 0; it < 4; ++it) {
    int f = tid + it * 256;
    int si = f >> 3;              // 0..127
    int c8 = f & 7;               // 8-chunk within 64-d row
    int s = sbase + si;
    U8 kr, vr;
    kr.u = make_uint4(0, 0, 0, 0); vr.u = make_uint4(0, 0, 0, 0);
    if (s >= 0 && s < TT) {
      kr.u = *(const uint4*)&kb[(size_t)s * 768 + 8 * c8];
      vr.u = *(const uint4*)&vb[(size_t)s * 768 + 8 * c8];
    }
    *(uint4*)&Ks[si][c8 * 8] = kr.u;
    int pc = (si >> 3) ^ c8;      // swizzled si-chunk (conflict-free writes)
#pragma unroll
    for (int j = 0; j < 8; ++j) Vt[(c8 * 8 + j) * 136 + pc * 8 + (si & 7)] = vr.hx[j];
  }
  __syncthreads();

  const int wave = tid >> 6, lane = tid & 63;
  const int quad = lane >> 4, lr = lane & 15;

  // --- QK^T ---
  const __hip_bfloat16* qrow = qkv + (size_t)(b * TT + t0 + wave * 16 + lr) * 768 + h * 64;
  bf16x8 qa0 = *(const bf16x8*)(qrow + quad * 8);
  bf16x8 qa1 = *(const bf16x8*)(qrow + 32 + quad * 8);
  f32x4 sc[8];
#pragma unroll
  for (int c = 0; c < 8; ++c) {
    f32x4 a = {};
    bf16x8 kf0 = *(const bf16x8*)&Ks[c * 16 + lr][quad * 8];
    a = __builtin_amdgcn_mfma_f32_16x16x32_bf16(qa0, kf0, a, 0, 0, 0);
    bf16x8 kf1 = *(const bf16x8*)&Ks[c * 16 + lr][32 + quad * 8];
    a = __builtin_amdgcn_mfma_f32_16x16x32_bf16(qa1, kf1, a, 0, 0, 0);
    sc[c] = a;
  }

  // --- masked softmax ---
#pragma unroll
  for (int reg = 0; reg < 4; ++reg) {
    int dt = wave * 16 + quad * 4 + reg;
    float pv[8];
    float mx = -1e30f;
#pragma unroll
    for (int c = 0; c < 8; ++c) {
      int si = c * 16 + lr;
      float v = sc[c][reg] * 0.125f;
      bool ok = (si >= dt) && (si <= dt + 63) && (sbase + si >= 0);
      v = ok ? v : -1e30f;
      pv[c] = v;
      mx = fmaxf(mx, v);
    }
#pragma unroll
    for (int off = 8; off; off >>= 1) mx = fmaxf(mx, __shfl_xor(mx, off, 64));
    float l = 0.f;
#pragma unroll
    for (int c = 0; c < 8; ++c) { float e = __expf(pv[c] - mx); pv[c] = e; l += e; }
#pragma unroll
    for (int off = 8; off; off >>= 1) l += __shfl_xor(l, off, 64);
    float rinv = 1.f / l;
#pragma unroll
    for (int c = 0; c < 8; ++c)
      Ps[wave][quad * 4 + reg][c * 16 + lr] = __float2bfloat16(pv[c] * rinv);
  }

  // --- O = P V ---
  __hip_bfloat16* obase = o + (size_t)(b * TT) * DD + h * 64;
#pragma unroll
  for (int ct = 0; ct < 4; ++ct) {
    f32x4 acc = {};
#pragma unroll
    for (int kk = 0; kk < 4; ++kk) {
      bf16x8 pa = *(const bf16x8*)&Ps[wave][lr][kk * 32 + quad * 8];
      int dd = ct * 16 + lr;
      bf16x8 vf = *(const bf16x8*)&Vt[dd * 136 + (((kk * 4 + quad) ^ (dd >> 3)) * 8)];
      acc = __builtin_amdgcn_mfma_f32_16x16x32_bf16(pa, vf, acc, 0, 0, 0);
    }
#pragma unroll
    for (int reg = 0; reg < 4; ++reg) {
      int t = t0 + wave * 16 + quad * 4 + reg;
      obase[(size_t)t * DD + ct * 16 + lr] = __float2bfloat16(acc[reg]);
    }
  }
}

extern "C" void kernel_launch(void* const* d_in, const int* in_sizes, int n_in,
                              void* d_out, int out_size, void* d_ws, size_t ws_size,
                              hipStream_t stream) {
  const float* tokens = (const float*)d_in[0];
  const float* Wqkv = (const float*)d_in[1];
  const float* bqkv = (const float*)d_in[2];
  const float* Wo   = (const float*)d_in[3];
  const float* bo   = (const float*)d_in[4];
  const float* W1   = (const float*)d_in[5];
  const float* b1   = (const float*)d_in[6];
  const float* W2   = (const float*)d_in[7];
  const float* b2   = (const float*)d_in[8];
  const float* ln1g = (const float*)d_in[9];
  const float* ln1b = (const float*)d_in[10];
  const float* ln2g = (const float*)d_in[11];
  const float* ln2b = (const float*)d_in[12];
  const float* lnfg = (const float*)d_in[13];
  const float* lnfb = (const float*)d_in[14];
  float* out = (float*)d_out;

  const int M = BB * TT;                 // 8192
  const int ND = M * DD;                 // 2097152

  float* x = (float*)d_ws;
  __hip_bfloat16* sb  = (__hip_bfloat16*)(x + ND);          // M*256 bf16
  __hip_bfloat16* big = sb + (size_t)M * DD;                // M*1024 bf16
  __hip_bfloat16* wqb = big + (size_t)M * FF;               // weights, contiguous
  __hip_bfloat16* wob = wqb + (size_t)NL * 3 * DD * DD;
  __hip_bfloat16* w1b = wob + (size_t)NL * DD * DD;
  __hip_bfloat16* w2b = w1b + (size_t)NL * FF * DD;

  f2b_all_kernel<<<3072, 256, 0, stream>>>(
      (const float4*)Wqkv, (const float4*)Wo, (const float4*)W1,
      (const float4*)W2, (ushort4*)wqb);

  pe_ln_kernel<<<M / 4, 256, 0, stream>>>(tokens, ln1g, ln1b, x, sb);

  for (int l = 0; l < NL; ++l) {
    // qkv: 128x96 tiles -> grid 512 = 2 blocks/CU exactly
    mgemm_kernel<4, 3, 0><<<dim3(768 / 96, M / 128), 256, 0, stream>>>(
        sb, wqb + (size_t)l * 768 * DD, bqkv + l * 768, big, M, 768, DD);
    attn_kernel<<<dim3(TT / 64, BB * 4), 256, 0, stream>>>(big, sb);
    // Wo + residual + ln2 fused
    mgemm_ln_kernel<0><<<M / 16, 256, 0, stream>>>(
        sb, wob + (size_t)l * DD * DD, bo + l * DD, x,
        ln2g + l * DD, ln2b + l * DD, x, sb, DD);
    // W1 + GELU
    mgemm_kernel<4, 4, 1><<<dim3(FF / 128, M / 128), 256, 0, stream>>>(
        sb, w1b + (size_t)l * FF * DD, b1 + l * FF, big, M, FF, DD);
    // W2 + residual + (ln1 of next layer | final LN -> d_out)
    if (l < NL - 1) {
      mgemm_ln_kernel<0><<<M / 16, 256, 0, stream>>>(
          big, w2b + (size_t)l * DD * FF, b2 + l * DD, x,
          ln1g + (l + 1) * DD, ln1b + (l + 1) * DD, x, sb, FF);
    } else {
      mgemm_ln_kernel<1><<<M / 16, 256, 0, stream>>>(
          big, w2b + (size_t)l * DD * FF, b2 + l * DD, x,
          lnfg, lnfb, nullptr, out, FF);
    }
  }
}